// Round 4
// baseline (229.061 us; speedup 1.0000x reference)
//
#include <hip/hip_runtime.h>
#include <math.h>

#define BB   4096
#define SS   5
#define DD   64
#define HSZ  961
#define VSA  1024
#define NT   256
#define NB   4      // batches per block
#define LNE  1e-3f

// padded h layout: P[r] = h[r-POFF] for r in [POFF, POFF+960], else 0
#define POFF 64
#define PW   1092   // max index accessed = 1091; rows 16B-aligned

__device__ __forceinline__ float silu_f(float x) { return x / (1.f + __expf(-x)); }

// ---- Kernel 1: sp = LN(silu(conv(symbols,h))); also emit zero-padded h ----
__global__ __launch_bounds__(NT)
void sp_kernel(const float* __restrict__ symbols, const float* __restrict__ h,
               const float* __restrict__ gamma, const float* __restrict__ beta,
               float* __restrict__ sp, float* __restrict__ hpadG)
{
    __shared__ float hpad[PW];
    __shared__ float red[4][2];
    const int s = blockIdx.x;
    const int tid = threadIdx.x;
    const int lane = tid & 63, wave = tid >> 6;

    for (int r = tid; r < PW; r += NT) {
        const float v = (r >= POFF && r <= POFF + 960) ? h[s * HSZ + (r - POFF)] : 0.f;
        hpad[r] = v;
        hpadG[s * PW + r] = v;        // padded copy for main_kernel
    }
    __syncthreads();

    const int base = 1020 - 4 * tid;
    float hw[8];
    *(float4*)&hw[0] = *(const float4*)&hpad[base];
    float acc[4] = {0.f, 0.f, 0.f, 0.f};
    const float* xp = symbols + s * DD;
#pragma unroll
    for (int c = 0; c < 16; c++) {
        *(float4*)&hw[4] = *(const float4*)&hpad[base + 4 * (c + 1)];
        const float x0 = xp[4 * c + 0];
        const float x1 = xp[4 * c + 1];
        const float x2 = xp[4 * c + 2];
        const float x3 = xp[4 * c + 3];
        acc[0] += x0 * hw[4]; acc[0] += x1 * hw[5]; acc[0] += x2 * hw[6]; acc[0] += x3 * hw[7];
        acc[1] += x0 * hw[3]; acc[1] += x1 * hw[4]; acc[1] += x2 * hw[5]; acc[1] += x3 * hw[6];
        acc[2] += x0 * hw[2]; acc[2] += x1 * hw[3]; acc[2] += x2 * hw[4]; acc[2] += x3 * hw[5];
        acc[3] += x0 * hw[1]; acc[3] += x1 * hw[2]; acc[3] += x2 * hw[3]; acc[3] += x3 * hw[4];
        hw[0] = hw[4]; hw[1] = hw[5]; hw[2] = hw[6]; hw[3] = hw[7];
    }

    float ys[4];
    float lsum = 0.f, lsq = 0.f;
#pragma unroll
    for (int j = 0; j < 4; j++) {
        ys[j] = silu_f(acc[j]);
        lsum += ys[j]; lsq += ys[j] * ys[j];
    }
#pragma unroll
    for (int off = 32; off; off >>= 1) {
        lsum += __shfl_down(lsum, off, 64);
        lsq  += __shfl_down(lsq,  off, 64);
    }
    if (lane == 0) { red[wave][0] = lsum; red[wave][1] = lsq; }
    __syncthreads();
    float s0 = 0.f, s1 = 0.f;
#pragma unroll
    for (int w = 0; w < 4; w++) { s0 += red[w][0]; s1 += red[w][1]; }
    const float mean = s0 * (1.f / VSA);
    const float rstd = rsqrtf(s1 * (1.f / VSA) - mean * mean + LNE);

    const float4 g4 = *(const float4*)&gamma[4 * tid];
    const float4 b4 = *(const float4*)&beta[4 * tid];
    float4 o;
    o.x = (ys[0] - mean) * rstd * g4.x + b4.x;
    o.y = (ys[1] - mean) * rstd * g4.y + b4.y;
    o.z = (ys[2] - mean) * rstd * g4.z + b4.z;
    o.w = (ys[3] - mean) * rstd * g4.w + b4.w;
    *(float4*)&sp[s * VSA + 4 * tid] = o;
}

// ------- Kernel 2: NB batches per block; h-window regs amortized x4 --------
__global__ __launch_bounds__(NT, 2)
void main_kernel(const float* __restrict__ values, const float* __restrict__ hpadG,
                 const float* __restrict__ sp, const float* __restrict__ gamma,
                 const float* __restrict__ beta, float* __restrict__ out)
{
    __shared__ float red[SS][NB][4][2];
    __shared__ int   scorered[NB][4][SS * SS];
    __shared__ float wbuf[NB][SS * SS];

    const int tid = threadIdx.x;
    const int lane = tid & 63, wave = tid >> 6;
    const int b0 = blockIdx.x * NB;
    const int base = 1020 - 4 * tid;

    float vp[NB][SS][4];   // conv->silu->LN results, t = 4*tid+j

    // conv + silu for all 5 s x NB batches; h window loaded once per (s,chunk)
#pragma unroll
    for (int s = 0; s < SS; s++) {
        const float* hp = hpadG + s * PW + base;
        float hw[8];
        *(float4*)&hw[0] = *(const float4*)hp;
        float acc[NB][4];
#pragma unroll
        for (int nb = 0; nb < NB; nb++)
            acc[nb][0] = acc[nb][1] = acc[nb][2] = acc[nb][3] = 0.f;
#pragma unroll
        for (int c = 0; c < 16; c++) {
            *(float4*)&hw[4] = *(const float4*)(hp + 4 * (c + 1));
#pragma unroll
            for (int nb = 0; nb < NB; nb++) {
                // block-uniform address -> s_load path; value feeds FMA as SGPR
                const float4 xv = *(const float4*)(values + (size_t)(b0 + nb) * (SS * DD) + s * DD + 4 * c);
                acc[nb][0] += xv.x * hw[4]; acc[nb][0] += xv.y * hw[5]; acc[nb][0] += xv.z * hw[6]; acc[nb][0] += xv.w * hw[7];
                acc[nb][1] += xv.x * hw[3]; acc[nb][1] += xv.y * hw[4]; acc[nb][1] += xv.z * hw[5]; acc[nb][1] += xv.w * hw[6];
                acc[nb][2] += xv.x * hw[2]; acc[nb][2] += xv.y * hw[3]; acc[nb][2] += xv.z * hw[4]; acc[nb][2] += xv.w * hw[5];
                acc[nb][3] += xv.x * hw[1]; acc[nb][3] += xv.y * hw[2]; acc[nb][3] += xv.z * hw[3]; acc[nb][3] += xv.w * hw[4];
            }
            hw[0] = hw[4]; hw[1] = hw[5]; hw[2] = hw[6]; hw[3] = hw[7];
        }
        // silu + LN partials per batch
#pragma unroll
        for (int nb = 0; nb < NB; nb++) {
            float lsum = 0.f, lsq = 0.f;
#pragma unroll
            for (int j = 0; j < 4; j++) {
                const float y = silu_f(acc[nb][j]);
                vp[nb][s][j] = y; lsum += y; lsq += y * y;
            }
#pragma unroll
            for (int off = 32; off; off >>= 1) {
                lsum += __shfl_down(lsum, off, 64);
                lsq  += __shfl_down(lsq,  off, 64);
            }
            if (lane == 0) { red[s][nb][wave][0] = lsum; red[s][nb][wave][1] = lsq; }
        }
    }
    __syncthreads();

    // LayerNorm epilogue in registers
    const float4 g4 = *(const float4*)&gamma[4 * tid];
    const float4 b4 = *(const float4*)&beta[4 * tid];
#pragma unroll
    for (int s = 0; s < SS; s++) {
#pragma unroll
        for (int nb = 0; nb < NB; nb++) {
            float s0 = 0.f, s1 = 0.f;
#pragma unroll
            for (int w = 0; w < 4; w++) { s0 += red[s][nb][w][0]; s1 += red[s][nb][w][1]; }
            const float mean = s0 * (1.f / VSA);
            const float rstd = rsqrtf(s1 * (1.f / VSA) - mean * mean + LNE);
            vp[nb][s][0] = (vp[nb][s][0] - mean) * rstd * g4.x + b4.x;
            vp[nb][s][1] = (vp[nb][s][1] - mean) * rstd * g4.y + b4.y;
            vp[nb][s][2] = (vp[nb][s][2] - mean) * rstd * g4.z + b4.z;
            vp[nb][s][3] = (vp[nb][s][3] - mean) * rstd * g4.w + b4.w;
        }
    }

    // sp fragments (batch-independent)
    float sp4[SS][4];
#pragma unroll
    for (int i = 0; i < SS; i++)
        *(float4*)&sp4[i][0] = *(const float4*)&sp[i * VSA + 4 * tid];

    // scores via ballot: sign(a)*sign(b) = 1 - 2*[signbits differ]
    // neq accumulates in SGPRs (ballot/popc are wave-uniform)
#pragma unroll
    for (int nb = 0; nb < NB; nb++) {
        int neq[SS * SS];
#pragma unroll
        for (int p = 0; p < SS * SS; p++) neq[p] = 0;
#pragma unroll
        for (int jj = 0; jj < 4; jj++) {
            unsigned long long bvi[SS];
#pragma unroll
            for (int i = 0; i < SS; i++) bvi[i] = __ballot(vp[nb][i][jj] > 0.f);
#pragma unroll
            for (int j = 0; j < SS; j++) {
                const float sjv = sp4[j][jj];
#pragma unroll
                for (int i = 0; i < SS; i++) {
                    const unsigned long long bs = __ballot(vp[nb][i][jj] + sjv > 0.f);
                    neq[j * SS + i] += (int)__popcll(bvi[i] ^ bs);
                }
            }
        }
        if (lane == 0) {
#pragma unroll
            for (int p = 0; p < SS * SS; p++) scorered[nb][wave][p] = neq[p];
        }
    }
    __syncthreads();

    // softmax over i per (nb, j) — 20 threads
    if (tid < NB * SS) {
        const int nb = tid / SS, j = tid - nb * SS;
        float sc[SS];
#pragma unroll
        for (int i = 0; i < SS; i++) {
            const int nq = scorered[nb][0][j * SS + i] + scorered[nb][1][j * SS + i]
                         + scorered[nb][2][j * SS + i] + scorered[nb][3][j * SS + i];
            sc[i] = 1.f - (2.f / VSA) * (float)nq;
        }
        float m = sc[0];
#pragma unroll
        for (int i = 1; i < SS; i++) m = fmaxf(m, sc[i]);
        float e[SS], ssum = 0.f;
#pragma unroll
        for (int i = 0; i < SS; i++) { e[i] = __expf(sc[i] - m); ssum += e[i]; }
        const float inv = 1.f / ssum;
#pragma unroll
        for (int i = 0; i < SS; i++) wbuf[nb][j * SS + i] = e[i] * inv;
    }
    __syncthreads();

    // out[b][j][t] = silu( (sum_i w[j][i]*vp[i][t]) * sp[j][t] )
#pragma unroll
    for (int nb = 0; nb < NB; nb++) {
        float wn[SS * SS];
#pragma unroll
        for (int p = 0; p < SS * SS; p++) wn[p] = wbuf[nb][p];   // LDS broadcast
        const size_t obase = (size_t)(b0 + nb) * SS * VSA + 4 * tid;
#pragma unroll
        for (int j = 0; j < SS; j++) {
            float att[4] = {0.f, 0.f, 0.f, 0.f};
#pragma unroll
            for (int i = 0; i < SS; i++) {
                const float wi = wn[j * SS + i];
#pragma unroll
                for (int e = 0; e < 4; e++) att[e] += wi * vp[nb][i][e];
            }
            float4 o;
            o.x = silu_f(att[0] * sp4[j][0]);
            o.y = silu_f(att[1] * sp4[j][1]);
            o.z = silu_f(att[2] * sp4[j][2]);
            o.w = silu_f(att[3] * sp4[j][3]);
            *(float4*)&out[obase + (size_t)j * VSA] = o;
        }
    }
}

extern "C" void kernel_launch(void* const* d_in, const int* in_sizes, int n_in,
                              void* d_out, int out_size, void* d_ws, size_t ws_size,
                              hipStream_t stream) {
    const float* values  = (const float*)d_in[0];
    const float* h       = (const float*)d_in[1];
    const float* symbols = (const float*)d_in[2];
    const float* gamma   = (const float*)d_in[3];
    const float* beta    = (const float*)d_in[4];
    float* out   = (float*)d_out;
    float* sp    = (float*)d_ws;                 // 5*1024 floats
    float* hpadG = (float*)d_ws + SS * VSA;      // 5*1092 floats (padded h)

    sp_kernel<<<SS, NT, 0, stream>>>(symbols, h, gamma, beta, sp, hpadG);
    main_kernel<<<BB / NB, NT, 0, stream>>>(values, hpadG, sp, gamma, beta, out);
}

// Round 6
// 211.590 us; speedup vs baseline: 1.0826x; 1.0826x over previous
//
#include <hip/hip_runtime.h>
#include <math.h>

#define BB   4096
#define SS   5
#define DD   64
#define HSZ  961
#define VSA  1024
#define NT   256
#define NB   2      // batches per block (NB=4 spilled: 190-reg live set @128 cap)
#define LNE  1e-3f

// padded h layout: P[r] = h[r-POFF] for r in [POFF, POFF+960], else 0
#define POFF 64
#define PW   1092   // max index accessed = 1091; rows 16B-aligned

typedef float v4f __attribute__((ext_vector_type(4)));   // native vec for nontemporal

__device__ __forceinline__ float silu_f(float x) { return x / (1.f + __expf(-x)); }

// ---- Kernel 1: sp = LN(silu(conv(symbols,h))); also emit zero-padded h ----
__global__ __launch_bounds__(NT)
void sp_kernel(const float* __restrict__ symbols, const float* __restrict__ h,
               const float* __restrict__ gamma, const float* __restrict__ beta,
               float* __restrict__ sp, float* __restrict__ hpadG)
{
    __shared__ float hpad[PW];
    __shared__ float red[4][2];
    const int s = blockIdx.x;
    const int tid = threadIdx.x;
    const int lane = tid & 63, wave = tid >> 6;

    for (int r = tid; r < PW; r += NT) {
        const float v = (r >= POFF && r <= POFF + 960) ? h[s * HSZ + (r - POFF)] : 0.f;
        hpad[r] = v;
        hpadG[s * PW + r] = v;        // padded copy for main_kernel
    }
    __syncthreads();

    const int base = 1020 - 4 * tid;
    float hw[8];
    *(float4*)&hw[0] = *(const float4*)&hpad[base];
    float acc[4] = {0.f, 0.f, 0.f, 0.f};
    const float* xp = symbols + s * DD;
#pragma unroll
    for (int c = 0; c < 16; c++) {
        *(float4*)&hw[4] = *(const float4*)&hpad[base + 4 * (c + 1)];
        const float x0 = xp[4 * c + 0];
        const float x1 = xp[4 * c + 1];
        const float x2 = xp[4 * c + 2];
        const float x3 = xp[4 * c + 3];
        acc[0] += x0 * hw[4]; acc[0] += x1 * hw[5]; acc[0] += x2 * hw[6]; acc[0] += x3 * hw[7];
        acc[1] += x0 * hw[3]; acc[1] += x1 * hw[4]; acc[1] += x2 * hw[5]; acc[1] += x3 * hw[6];
        acc[2] += x0 * hw[2]; acc[2] += x1 * hw[3]; acc[2] += x2 * hw[4]; acc[2] += x3 * hw[5];
        acc[3] += x0 * hw[1]; acc[3] += x1 * hw[2]; acc[3] += x2 * hw[3]; acc[3] += x3 * hw[4];
        hw[0] = hw[4]; hw[1] = hw[5]; hw[2] = hw[6]; hw[3] = hw[7];
    }

    float ys[4];
    float lsum = 0.f, lsq = 0.f;
#pragma unroll
    for (int j = 0; j < 4; j++) {
        ys[j] = silu_f(acc[j]);
        lsum += ys[j]; lsq += ys[j] * ys[j];
    }
#pragma unroll
    for (int off = 32; off; off >>= 1) {
        lsum += __shfl_down(lsum, off, 64);
        lsq  += __shfl_down(lsq,  off, 64);
    }
    if (lane == 0) { red[wave][0] = lsum; red[wave][1] = lsq; }
    __syncthreads();
    float s0 = 0.f, s1 = 0.f;
#pragma unroll
    for (int w = 0; w < 4; w++) { s0 += red[w][0]; s1 += red[w][1]; }
    const float mean = s0 * (1.f / VSA);
    const float rstd = rsqrtf(s1 * (1.f / VSA) - mean * mean + LNE);

    const float4 g4 = *(const float4*)&gamma[4 * tid];
    const float4 b4 = *(const float4*)&beta[4 * tid];
    float4 o;
    o.x = (ys[0] - mean) * rstd * g4.x + b4.x;
    o.y = (ys[1] - mean) * rstd * g4.y + b4.y;
    o.z = (ys[2] - mean) * rstd * g4.z + b4.z;
    o.w = (ys[3] - mean) * rstd * g4.w + b4.w;
    *(float4*)&sp[s * VSA + 4 * tid] = o;
}

// ------- Kernel 2: NB=2 batches per block; no spills (live set ~100 regs) ---
__global__ __launch_bounds__(NT, 2)
void main_kernel(const float* __restrict__ values, const float* __restrict__ hpadG,
                 const float* __restrict__ sp, const float* __restrict__ gamma,
                 const float* __restrict__ beta, float* __restrict__ out)
{
    __shared__ float red[SS][NB][4][2];
    __shared__ int   scorered[NB][4][SS * SS];
    __shared__ float wbuf[NB][SS * SS];

    const int tid = threadIdx.x;
    const int lane = tid & 63, wave = tid >> 6;
    const int b0 = blockIdx.x * NB;
    const int base = 1020 - 4 * tid;

    float vp[NB][SS][4];   // conv->silu->LN results, t = 4*tid+j

    // conv + silu for all 5 s x NB batches; h window loaded once per (s,chunk)
#pragma unroll
    for (int s = 0; s < SS; s++) {
        const float* hp = hpadG + s * PW + base;
        float hw[8];
        *(float4*)&hw[0] = *(const float4*)hp;
        float acc[NB][4];
#pragma unroll
        for (int nb = 0; nb < NB; nb++)
            acc[nb][0] = acc[nb][1] = acc[nb][2] = acc[nb][3] = 0.f;
#pragma unroll
        for (int c = 0; c < 16; c++) {
            *(float4*)&hw[4] = *(const float4*)(hp + 4 * (c + 1));
#pragma unroll
            for (int nb = 0; nb < NB; nb++) {
                // block-uniform address -> s_load path; value feeds FMA as SGPR
                const float4 xv = *(const float4*)(values + (size_t)(b0 + nb) * (SS * DD) + s * DD + 4 * c);
                acc[nb][0] += xv.x * hw[4]; acc[nb][0] += xv.y * hw[5]; acc[nb][0] += xv.z * hw[6]; acc[nb][0] += xv.w * hw[7];
                acc[nb][1] += xv.x * hw[3]; acc[nb][1] += xv.y * hw[4]; acc[nb][1] += xv.z * hw[5]; acc[nb][1] += xv.w * hw[6];
                acc[nb][2] += xv.x * hw[2]; acc[nb][2] += xv.y * hw[3]; acc[nb][2] += xv.z * hw[4]; acc[nb][2] += xv.w * hw[5];
                acc[nb][3] += xv.x * hw[1]; acc[nb][3] += xv.y * hw[2]; acc[nb][3] += xv.z * hw[3]; acc[nb][3] += xv.w * hw[4];
            }
            hw[0] = hw[4]; hw[1] = hw[5]; hw[2] = hw[6]; hw[3] = hw[7];
        }
        // silu + LN partials per batch
#pragma unroll
        for (int nb = 0; nb < NB; nb++) {
            float lsum = 0.f, lsq = 0.f;
#pragma unroll
            for (int j = 0; j < 4; j++) {
                const float y = silu_f(acc[nb][j]);
                vp[nb][s][j] = y; lsum += y; lsq += y * y;
            }
#pragma unroll
            for (int off = 32; off; off >>= 1) {
                lsum += __shfl_down(lsum, off, 64);
                lsq  += __shfl_down(lsq,  off, 64);
            }
            if (lane == 0) { red[s][nb][wave][0] = lsum; red[s][nb][wave][1] = lsq; }
        }
    }
    __syncthreads();

    // LayerNorm epilogue in registers
    const float4 g4 = *(const float4*)&gamma[4 * tid];
    const float4 b4 = *(const float4*)&beta[4 * tid];
#pragma unroll
    for (int s = 0; s < SS; s++) {
#pragma unroll
        for (int nb = 0; nb < NB; nb++) {
            float s0 = 0.f, s1 = 0.f;
#pragma unroll
            for (int w = 0; w < 4; w++) { s0 += red[s][nb][w][0]; s1 += red[s][nb][w][1]; }
            const float mean = s0 * (1.f / VSA);
            const float rstd = rsqrtf(s1 * (1.f / VSA) - mean * mean + LNE);
            vp[nb][s][0] = (vp[nb][s][0] - mean) * rstd * g4.x + b4.x;
            vp[nb][s][1] = (vp[nb][s][1] - mean) * rstd * g4.y + b4.y;
            vp[nb][s][2] = (vp[nb][s][2] - mean) * rstd * g4.z + b4.z;
            vp[nb][s][3] = (vp[nb][s][3] - mean) * rstd * g4.w + b4.w;
        }
    }

    // sp fragments (batch-independent, L1/L2-hot)
    float sp4[SS][4];
#pragma unroll
    for (int i = 0; i < SS; i++)
        *(float4*)&sp4[i][0] = *(const float4*)&sp[i * VSA + 4 * tid];

    // scores via ballot: sign(a)*sign(b) = 1 - 2*[signbits differ]
#pragma unroll
    for (int nb = 0; nb < NB; nb++) {
        int neq[SS * SS];
#pragma unroll
        for (int p = 0; p < SS * SS; p++) neq[p] = 0;
#pragma unroll
        for (int jj = 0; jj < 4; jj++) {
            unsigned long long bvi[SS];
#pragma unroll
            for (int i = 0; i < SS; i++) bvi[i] = __ballot(vp[nb][i][jj] > 0.f);
#pragma unroll
            for (int j = 0; j < SS; j++) {
                const float sjv = sp4[j][jj];
#pragma unroll
                for (int i = 0; i < SS; i++) {
                    const unsigned long long bs = __ballot(vp[nb][i][jj] + sjv > 0.f);
                    neq[j * SS + i] += (int)__popcll(bvi[i] ^ bs);
                }
            }
        }
        if (lane == 0) {
#pragma unroll
            for (int p = 0; p < SS * SS; p++) scorered[nb][wave][p] = neq[p];
        }
    }
    __syncthreads();

    // softmax over i per (nb, j) — NB*SS threads
    if (tid < NB * SS) {
        const int nb = tid / SS, j = tid - nb * SS;
        float sc[SS];
#pragma unroll
        for (int i = 0; i < SS; i++) {
            const int nq = scorered[nb][0][j * SS + i] + scorered[nb][1][j * SS + i]
                         + scorered[nb][2][j * SS + i] + scorered[nb][3][j * SS + i];
            sc[i] = 1.f - (2.f / VSA) * (float)nq;
        }
        float m = sc[0];
#pragma unroll
        for (int i = 1; i < SS; i++) m = fmaxf(m, sc[i]);
        float e[SS], ssum = 0.f;
#pragma unroll
        for (int i = 0; i < SS; i++) { e[i] = __expf(sc[i] - m); ssum += e[i]; }
        const float inv = 1.f / ssum;
#pragma unroll
        for (int i = 0; i < SS; i++) wbuf[nb][j * SS + i] = e[i] * inv;
    }
    __syncthreads();

    // out[b][j][t] = silu( (sum_i w[j][i]*vp[i][t]) * sp[j][t] )
#pragma unroll
    for (int nb = 0; nb < NB; nb++) {
        const size_t obase = (size_t)(b0 + nb) * SS * VSA + 4 * tid;
#pragma unroll
        for (int j = 0; j < SS; j++) {
            float wj[SS];
#pragma unroll
            for (int i = 0; i < SS; i++) wj[i] = wbuf[nb][j * SS + i];  // LDS broadcast
            float att[4] = {0.f, 0.f, 0.f, 0.f};
#pragma unroll
            for (int i = 0; i < SS; i++) {
                const float wi = wj[i];
#pragma unroll
                for (int e = 0; e < 4; e++) att[e] += wi * vp[nb][i][e];
            }
            v4f o;
            o.x = silu_f(att[0] * sp4[j][0]);
            o.y = silu_f(att[1] * sp4[j][1]);
            o.z = silu_f(att[2] * sp4[j][2]);
            o.w = silu_f(att[3] * sp4[j][3]);
            __builtin_nontemporal_store(o, (v4f*)&out[obase + (size_t)j * VSA]);
        }
    }
}

extern "C" void kernel_launch(void* const* d_in, const int* in_sizes, int n_in,
                              void* d_out, int out_size, void* d_ws, size_t ws_size,
                              hipStream_t stream) {
    const float* values  = (const float*)d_in[0];
    const float* h       = (const float*)d_in[1];
    const float* symbols = (const float*)d_in[2];
    const float* gamma   = (const float*)d_in[3];
    const float* beta    = (const float*)d_in[4];
    float* out   = (float*)d_out;
    float* sp    = (float*)d_ws;                 // 5*1024 floats
    float* hpadG = (float*)d_ws + SS * VSA;      // 5*1092 floats (padded h)

    sp_kernel<<<SS, NT, 0, stream>>>(symbols, h, gamma, beta, sp, hpadG);
    main_kernel<<<BB / NB, NT, 0, stream>>>(values, hpadG, sp, gamma, beta, out);
}